// Round 7
// baseline (127.270 us; speedup 1.0000x reference)
//
#include <hip/hip_runtime.h>
#include <math.h>

#define LRELU_ALPHA 0.2f

typedef __attribute__((ext_vector_type(8))) short bf16x8;
typedef __attribute__((ext_vector_type(4))) float f32x4;

// truncation split: f ~= hi + lo with hi,lo bf16 (RTZ); combined error ~2^-16 rel.
// packs two elements: low 16 bits of 'hi' = f0's bf16, high 16 = f1's.
__device__ __forceinline__ void split2(float f0, float f1, unsigned& hi, unsigned& lo) {
    unsigned u0 = __float_as_uint(f0), u1 = __float_as_uint(f1);
    unsigned h0 = u0 & 0xFFFF0000u, h1 = u1 & 0xFFFF0000u;
    float l0f = f0 - __uint_as_float(h0);
    float l1f = f1 - __uint_as_float(h1);
    hi = (h0 >> 16) | h1;
    lo = (__float_as_uint(l0f) >> 16) | (__float_as_uint(l1f) & 0xFFFF0000u);
}

// ------------- zero the counts buffer (replaces hipMemsetAsync: runtime fill
// kernel cost ~41 us/replay in-graph; this is ~2 us) -------------
__global__ __launch_bounds__(256) void k_zero(int* __restrict__ p, int n) {
    int i = blockIdx.x * 256 + threadIdx.x;
    if (i < n) p[i] = 0;
}

// ---------------- W prep: split W into bf16 hi/lo in fragment-major layout ----------------
// fid = ((ct*4+ks)*64 + lane); wf[fid] = hi frag, wf[2048+fid] = lo frag.
// Fragment: lane holds W[ct*16+(lane&15)][ks*32+(lane>>4)*8 .. +7]
__global__ __launch_bounds__(256) void k_wprep(const float* __restrict__ W,
                                               bf16x8* __restrict__ wf) {
    int id = blockIdx.x * 256 + threadIdx.x;   // 0..2047
    int lane = id & 63, ks = (id >> 6) & 3, ct = id >> 8;
    int j = ct * 16 + (lane & 15);
    int k0 = ks * 32 + ((lane >> 4) << 3);
    const float* wp = W + j * 128 + k0;
    float4 f0 = *reinterpret_cast<const float4*>(wp);
    float4 f1 = *reinterpret_cast<const float4*>(wp + 4);
    uint4 hv, lv;
    split2(f0.x, f0.y, hv.x, lv.x);
    split2(f0.z, f0.w, hv.y, lv.y);
    split2(f1.x, f1.y, hv.z, lv.z);
    split2(f1.z, f1.w, hv.w, lv.w);
    *reinterpret_cast<uint4*>(&wf[id]) = hv;
    *reinterpret_cast<uint4*>(&wf[2048 + id]) = lv;
}

// ---------------- MFMA GEMM + fused alpha ----------------
// h[n][j] = b[j] + sum_k x[n][k]*W[j][k]; split-bf16 (xh*wh + xh*wl + xl*wh).
// Block: 64 rows x 128 cols, 4 waves; wave w owns col-tiles {2w,2w+1} = head w.
// Epilogue: asrc[n][w], adst[n][w] via 16-lane shfl reduction of live accumulators.
__global__ __launch_bounds__(256) void k_gemm(const float* __restrict__ x,
                                              const bf16x8* __restrict__ wf,
                                              const float* __restrict__ b,
                                              const float* __restrict__ a,
                                              float* __restrict__ h,
                                              float* __restrict__ asrc,
                                              float* __restrict__ adst, int N) {
    __shared__ __align__(16) unsigned char sXH[64 * 256];
    __shared__ __align__(16) unsigned char sXL[64 * 256];
    const int t = threadIdx.x;
    const int w = t >> 6;          // wave 0..3 == head
    const int l = t & 63;          // lane
    const int base = blockIdx.x * 64;

    // W fragments: coalesced 16B loads from fragment-major buffer
    bf16x8 wh[2][4], wl[2][4];
    #pragma unroll
    for (int ctl = 0; ctl < 2; ++ctl)
        #pragma unroll
        for (int ks = 0; ks < 4; ++ks) {
            int fid = (((2 * w + ctl) * 4 + ks) << 6) + l;
            wh[ctl][ks] = wf[fid];
            wl[ctl][ks] = wf[2048 + fid];
        }

    int jj[2];
    float bv[2], asw[2], adw[2];
    #pragma unroll
    for (int ctl = 0; ctl < 2; ++ctl) {
        jj[ctl] = w * 32 + ctl * 16 + (l & 15);
        bv[ctl] = b[jj[ctl]];
        asw[ctl] = a[w * 64 + ctl * 16 + (l & 15)];
        adw[ctl] = a[w * 64 + 32 + ctl * 16 + (l & 15)];
    }

    // stage x tile -> LDS bf16 hi/lo, XOR-swizzled (byte ^= (row&7)<<4)
    #pragma unroll
    for (int i = 0; i < 8; ++i) {
        int f = t + i * 256;            // float4 index in 64x128 tile
        int r = f >> 5, c4 = f & 31;
        int gr = base + r;
        float4 v = (gr < N) ? *reinterpret_cast<const float4*>(x + (size_t)gr * 128 + c4 * 4)
                            : make_float4(0.f, 0.f, 0.f, 0.f);
        unsigned h01, h23, l01, l23;
        split2(v.x, v.y, h01, l01);
        split2(v.z, v.w, h23, l23);
        int boff = r * 256 + ((c4 * 8) ^ ((r & 7) << 4));
        *reinterpret_cast<uint2*>(sXH + boff) = make_uint2(h01, h23);
        *reinterpret_cast<uint2*>(sXL + boff) = make_uint2(l01, l23);
    }
    __syncthreads();

    f32x4 acc[4][2];
    #pragma unroll
    for (int rt = 0; rt < 4; ++rt)
        #pragma unroll
        for (int ctl = 0; ctl < 2; ++ctl)
            acc[rt][ctl] = (f32x4){0.f, 0.f, 0.f, 0.f};

    #pragma unroll
    for (int ks = 0; ks < 4; ++ks) {
        #pragma unroll
        for (int rt = 0; rt < 4; ++rt) {
            int r = rt * 16 + (l & 15);
            int boff = r * 256 + (((ks * 64) + ((l >> 4) << 4)) ^ ((r & 7) << 4));
            bf16x8 xh = *reinterpret_cast<const bf16x8*>(sXH + boff);
            bf16x8 xl = *reinterpret_cast<const bf16x8*>(sXL + boff);
            #pragma unroll
            for (int ctl = 0; ctl < 2; ++ctl) {
                acc[rt][ctl] = __builtin_amdgcn_mfma_f32_16x16x32_bf16(xh, wh[ctl][ks], acc[rt][ctl], 0, 0, 0);
                acc[rt][ctl] = __builtin_amdgcn_mfma_f32_16x16x32_bf16(xh, wl[ctl][ks], acc[rt][ctl], 0, 0, 0);
                acc[rt][ctl] = __builtin_amdgcn_mfma_f32_16x16x32_bf16(xl, wh[ctl][ks], acc[rt][ctl], 0, 0, 0);
            }
        }
    }

    // epilogue: store h + fused alpha. C/D: col=lane&15 (j), row=(lane>>4)*4+reg (n)
    #pragma unroll
    for (int rt = 0; rt < 4; ++rt) {
        #pragma unroll
        for (int reg = 0; reg < 4; ++reg) {
            int n = base + rt * 16 + ((l >> 4) << 2) + reg;
            bool ok = (n < N);
            float v0 = acc[rt][0][reg] + bv[0];
            float v1 = acc[rt][1][reg] + bv[1];
            if (ok) {
                h[(size_t)n * 128 + jj[0]] = v0;
                h[(size_t)n * 128 + jj[1]] = v1;
            }
            float ps = v0 * asw[0] + v1 * asw[1];
            float pd = v0 * adw[0] + v1 * adw[1];
            #pragma unroll
            for (int mask = 1; mask <= 8; mask <<= 1) {
                ps += __shfl_xor(ps, mask);
                pd += __shfl_xor(pd, mask);
            }
            if (ok && (l & 15) == 0) {
                asrc[n * 4 + w] = ps;
                adst[n * 4 + w] = pd;
            }
        }
    }
}

// ------------- CSR build -------------
__global__ __launch_bounds__(256) void k_hist(const int* __restrict__ edges,
                                              int* __restrict__ counts, int E) {
    int e = blockIdx.x * 256 + threadIdx.x;
    if (e < E) atomicAdd(&counts[edges[e * 2]], 1);
}

__global__ __launch_bounds__(256) void k_scan1(const int* __restrict__ counts,
                                               int* __restrict__ partial,
                                               int* __restrict__ bsum, int N) {
    __shared__ int sh[256];
    int i = blockIdx.x * 256 + threadIdx.x;
    sh[threadIdx.x] = (i < N) ? counts[i] : 0;
    __syncthreads();
    for (int off = 1; off < 256; off <<= 1) {
        int v = (threadIdx.x >= off) ? sh[threadIdx.x - off] : 0;
        __syncthreads();
        sh[threadIdx.x] += v;
        __syncthreads();
    }
    if (i < N) partial[i] = sh[threadIdx.x];
    if (threadIdx.x == 255) bsum[blockIdx.x] = sh[255];
}

__global__ __launch_bounds__(256) void k_scan2(int* __restrict__ bsum, int nb) {
    __shared__ int sh[256];
    sh[threadIdx.x] = (threadIdx.x < nb) ? bsum[threadIdx.x] : 0;
    __syncthreads();
    for (int off = 1; off < 256; off <<= 1) {
        int v = (threadIdx.x >= off) ? sh[threadIdx.x - off] : 0;
        __syncthreads();
        sh[threadIdx.x] += v;
        __syncthreads();
    }
    if (threadIdx.x < nb) bsum[threadIdx.x] = sh[threadIdx.x];
}

// row_ptr + cursor init — cursor from block-local values only (no cross-block read)
__global__ __launch_bounds__(256) void k_scan3(const int* __restrict__ partial,
                                               const int* __restrict__ bsum,
                                               const int* __restrict__ counts,
                                               int* __restrict__ row_ptr,
                                               int* __restrict__ cursor, int N) {
    int i = blockIdx.x * 256 + threadIdx.x;
    if (i == 0) row_ptr[0] = 0;
    if (i < N) {
        int incl = partial[i] + (blockIdx.x > 0 ? bsum[blockIdx.x - 1] : 0);
        row_ptr[i + 1] = incl;
        cursor[i] = incl - counts[i];
    }
}

// scatter dst ids into CSR slots AND precompute exp(lrelu(logit)) per edge*head.
// Softmax is shift-invariant -> no segment-max needed (logits ~N(0,2.8), exp safe in f32).
__global__ __launch_bounds__(256) void k_scatter(const int* __restrict__ edges,
                                                 int* __restrict__ cursor,
                                                 const float* __restrict__ asrc,
                                                 const float* __restrict__ adst,
                                                 int* __restrict__ col,
                                                 float* __restrict__ exv, int E) {
    int e = blockIdx.x * 256 + threadIdx.x;
    if (e >= E) return;
    int s = edges[e * 2], d = edges[e * 2 + 1];
    int pos = atomicAdd(&cursor[s], 1);
    col[pos] = d;
    float4 as4 = *reinterpret_cast<const float4*>(&asrc[s * 4]);
    float4 ad4 = *reinterpret_cast<const float4*>(&adst[d * 4]);
    float l0 = as4.x + ad4.x, l1 = as4.y + ad4.y, l2 = as4.z + ad4.z, l3 = as4.w + ad4.w;
    l0 = (l0 >= 0.f) ? l0 : LRELU_ALPHA * l0;
    l1 = (l1 >= 0.f) ? l1 : LRELU_ALPHA * l1;
    l2 = (l2 >= 0.f) ? l2 : LRELU_ALPHA * l2;
    l3 = (l3 >= 0.f) ? l3 : LRELU_ALPHA * l3;
    float4 ev;
    ev.x = __expf(l0); ev.y = __expf(l1); ev.z = __expf(l2); ev.w = __expf(l3);
    *reinterpret_cast<float4*>(&exv[(size_t)pos * 4]) = ev;
}

// ------------- per-node aggregate: out[n][:] = sum_k exv[k]*h[col[k]][:] / sum exv -------------
__global__ __launch_bounds__(256) void k_node(const int* __restrict__ row_ptr,
                                              const int* __restrict__ col,
                                              const float* __restrict__ exv,
                                              const float* __restrict__ h,
                                              float* __restrict__ out, int N) {
    int n = blockIdx.x * 8 + (threadIdx.x >> 5);
    if (n >= N) return;
    int l = threadIdx.x & 31;      // channel group: channels 4l..4l+3
    int hd = l >> 3;
    int beg = row_ptr[n], end = row_ptr[n + 1];
    float ax = 0.f, ay = 0.f, az = 0.f, aw = 0.f;
    float den = 0.f;
    int k = beg;
    for (; k + 4 <= end; k += 4) {
        int c0 = col[k], c1 = col[k + 1], c2 = col[k + 2], c3 = col[k + 3];
        float e0 = exv[(size_t)(k + 0) * 4 + hd];
        float e1 = exv[(size_t)(k + 1) * 4 + hd];
        float e2 = exv[(size_t)(k + 2) * 4 + hd];
        float e3 = exv[(size_t)(k + 3) * 4 + hd];
        float4 h0 = *reinterpret_cast<const float4*>(&h[(size_t)c0 * 128 + l * 4]);
        float4 h1 = *reinterpret_cast<const float4*>(&h[(size_t)c1 * 128 + l * 4]);
        float4 h2 = *reinterpret_cast<const float4*>(&h[(size_t)c2 * 128 + l * 4]);
        float4 h3 = *reinterpret_cast<const float4*>(&h[(size_t)c3 * 128 + l * 4]);
        ax += e0 * h0.x + e1 * h1.x + e2 * h2.x + e3 * h3.x;
        ay += e0 * h0.y + e1 * h1.y + e2 * h2.y + e3 * h3.y;
        az += e0 * h0.z + e1 * h1.z + e2 * h2.z + e3 * h3.z;
        aw += e0 * h0.w + e1 * h1.w + e2 * h2.w + e3 * h3.w;
        den += e0 + e1 + e2 + e3;
    }
    for (; k < end; ++k) {
        int c = col[k];
        float ev = exv[(size_t)k * 4 + hd];
        float4 hv = *reinterpret_cast<const float4*>(&h[(size_t)c * 128 + l * 4]);
        ax += ev * hv.x; ay += ev * hv.y; az += ev * hv.z; aw += ev * hv.w;
        den += ev;
    }
    float inv = 1.f / den;
    float4 o = make_float4(ax * inv, ay * inv, az * inv, aw * inv);
    *reinterpret_cast<float4*>(&out[(size_t)n * 128 + l * 4]) = o;
}

extern "C" void kernel_launch(void* const* d_in, const int* in_sizes, int n_in,
                              void* d_out, int out_size, void* d_ws, size_t ws_size,
                              hipStream_t stream) {
    const float* x = (const float*)d_in[0];
    const float* W = (const float*)d_in[1];
    const float* b = (const float*)d_in[2];
    const float* a = (const float*)d_in[3];
    const int* edges = (const int*)d_in[4];
    const int N = in_sizes[0] / 128;
    const int E = in_sizes[4] / 2;
    float* out = (float*)d_out;

    char* ws = (char*)d_ws;
    float* h = (float*)ws;        ws += (size_t)N * 128 * 4;
    float* asrc = (float*)ws;     ws += (size_t)N * 4 * 4;
    float* adst = (float*)ws;     ws += (size_t)N * 4 * 4;
    int* counts = (int*)ws;       ws += (size_t)N * 4;
    int* partial = (int*)ws;      ws += (size_t)N * 4;
    int* bsum = (int*)ws;         ws += 256 * 4;
    int* row_ptr = (int*)ws;      ws += (size_t)(N + 1) * 4;
    int* cursor = (int*)ws;       ws += (size_t)N * 4;
    int* col = (int*)ws;          ws += (size_t)E * 4;
    float* exv = (float*)ws;      ws += (size_t)E * 4 * 4;
    bf16x8* wf = (bf16x8*)ws;     ws += (size_t)4096 * 16;   // 64 KB: hi[2048] + lo[2048]

    const int nb = (N + 255) / 256;
    hipLaunchKernelGGL(k_zero, dim3(nb), dim3(256), 0, stream, counts, N);
    hipLaunchKernelGGL(k_wprep, dim3(8), dim3(256), 0, stream, W, wf);
    hipLaunchKernelGGL(k_gemm, dim3((N + 63) / 64), dim3(256), 0, stream,
                       x, wf, b, a, h, asrc, adst, N);

    const int eb = (E + 255) / 256;
    hipLaunchKernelGGL(k_hist, dim3(eb), dim3(256), 0, stream, edges, counts, E);
    hipLaunchKernelGGL(k_scan1, dim3(nb), dim3(256), 0, stream, counts, partial, bsum, N);
    hipLaunchKernelGGL(k_scan2, dim3(1), dim3(256), 0, stream, bsum, nb);
    hipLaunchKernelGGL(k_scan3, dim3(nb), dim3(256), 0, stream, partial, bsum, counts, row_ptr, cursor, N);
    hipLaunchKernelGGL(k_scatter, dim3(eb), dim3(256), 0, stream, edges, cursor, asrc, adst, col, exv, E);

    hipLaunchKernelGGL(k_node, dim3((N + 7) / 8), dim3(256), 0, stream,
                       row_ptr, col, exv, h, out, N);
}

// Round 8
// 104.379 us; speedup vs baseline: 1.2193x; 1.2193x over previous
//
#include <hip/hip_runtime.h>
#include <math.h>

#define LRELU_ALPHA 0.2f

typedef __attribute__((ext_vector_type(8))) short bf16x8;
typedef __attribute__((ext_vector_type(4))) float f32x4;

// truncation split: f ~= hi + lo with hi,lo bf16 (RTZ); combined error ~2^-16 rel.
__device__ __forceinline__ void split2(float f0, float f1, unsigned& hi, unsigned& lo) {
    unsigned u0 = __float_as_uint(f0), u1 = __float_as_uint(f1);
    unsigned h0 = u0 & 0xFFFF0000u, h1 = u1 & 0xFFFF0000u;
    float l0f = f0 - __uint_as_float(h0);
    float l1f = f1 - __uint_as_float(h1);
    hi = (h0 >> 16) | h1;
    lo = (__float_as_uint(l0f) >> 16) | (__float_as_uint(l1f) & 0xFFFF0000u);
}
// RNE f32 -> bf16
__device__ __forceinline__ unsigned short f2bf(float f) {
    unsigned u = __float_as_uint(f);
    return (unsigned short)((u + 0x7FFFu + ((u >> 16) & 1u)) >> 16);
}
__device__ __forceinline__ float bf2f(unsigned short s) {
    return __uint_as_float(((unsigned)s) << 16);
}

// ---------------- init: zero counts (all blocks) + W split (blocks 0..7) ----------------
// wf fragment-major: fid = ((ct*4+ks)*64+lane); wf[fid]=hi, wf[2048+fid]=lo.
// Fragment: lane holds W[ct*16+(lane&15)][ks*32+(lane>>4)*8 .. +7]
__global__ __launch_bounds__(256) void k_init(const float* __restrict__ W,
                                              bf16x8* __restrict__ wf,
                                              int* __restrict__ counts, int N) {
    int i = blockIdx.x * 256 + threadIdx.x;
    if (i < N) counts[i] = 0;
    if (blockIdx.x < 8) {
        int id = i;   // 0..2047
        int lane = id & 63, ks = (id >> 6) & 3, ct = id >> 8;
        int j = ct * 16 + (lane & 15);
        int k0 = ks * 32 + ((lane >> 4) << 3);
        const float* wp = W + j * 128 + k0;
        float4 f0 = *reinterpret_cast<const float4*>(wp);
        float4 f1 = *reinterpret_cast<const float4*>(wp + 4);
        uint4 hv, lv;
        split2(f0.x, f0.y, hv.x, lv.x);
        split2(f0.z, f0.w, hv.y, lv.y);
        split2(f1.x, f1.y, hv.z, lv.z);
        split2(f1.z, f1.w, hv.w, lv.w);
        *reinterpret_cast<uint4*>(&wf[id]) = hv;
        *reinterpret_cast<uint4*>(&wf[2048 + id]) = lv;
    }
}

// ---------------- MFMA GEMM + fused alpha; h stored bf16 ----------------
// Block: 32 rows x 128 cols, 4 waves; wave w = head w (col-tiles 2w,2w+1).
// split-bf16: h = xh*wh + xh*wl + xl*wh (f32 accum); store h as bf16 RNE.
__global__ __launch_bounds__(256) void k_gemm(const float* __restrict__ x,
                                              const bf16x8* __restrict__ wf,
                                              const float* __restrict__ b,
                                              const float* __restrict__ a,
                                              unsigned short* __restrict__ hb,
                                              float* __restrict__ asrc,
                                              float* __restrict__ adst, int N) {
    __shared__ __align__(16) unsigned char sXH[32 * 256];
    __shared__ __align__(16) unsigned char sXL[32 * 256];
    const int t = threadIdx.x;
    const int w = t >> 6;          // wave 0..3 == head
    const int l = t & 63;
    const int base = blockIdx.x * 32;

    // W fragments: coalesced 16B loads
    bf16x8 wh[2][4], wl[2][4];
    #pragma unroll
    for (int ctl = 0; ctl < 2; ++ctl)
        #pragma unroll
        for (int ks = 0; ks < 4; ++ks) {
            int fid = (((2 * w + ctl) * 4 + ks) << 6) + l;
            wh[ctl][ks] = wf[fid];
            wl[ctl][ks] = wf[2048 + fid];
        }

    int jj[2];
    float bv[2], asw[2], adw[2];
    #pragma unroll
    for (int ctl = 0; ctl < 2; ++ctl) {
        jj[ctl] = w * 32 + ctl * 16 + (l & 15);
        bv[ctl] = b[jj[ctl]];
        asw[ctl] = a[w * 64 + ctl * 16 + (l & 15)];
        adw[ctl] = a[w * 64 + 32 + ctl * 16 + (l & 15)];
    }

    // stage x tile (32 rows) -> LDS bf16 hi/lo, XOR-swizzled
    #pragma unroll
    for (int i = 0; i < 4; ++i) {
        int f = t + i * 256;            // float4 index in 32x128 tile
        int r = f >> 5, c4 = f & 31;
        int gr = base + r;
        float4 v = (gr < N) ? *reinterpret_cast<const float4*>(x + (size_t)gr * 128 + c4 * 4)
                            : make_float4(0.f, 0.f, 0.f, 0.f);
        unsigned h01, h23, l01, l23;
        split2(v.x, v.y, h01, l01);
        split2(v.z, v.w, h23, l23);
        int boff = r * 256 + ((c4 * 8) ^ ((r & 7) << 4));
        *reinterpret_cast<uint2*>(sXH + boff) = make_uint2(h01, h23);
        *reinterpret_cast<uint2*>(sXL + boff) = make_uint2(l01, l23);
    }
    __syncthreads();

    f32x4 acc[2][2];
    #pragma unroll
    for (int rt = 0; rt < 2; ++rt)
        #pragma unroll
        for (int ctl = 0; ctl < 2; ++ctl)
            acc[rt][ctl] = (f32x4){0.f, 0.f, 0.f, 0.f};

    #pragma unroll
    for (int ks = 0; ks < 4; ++ks) {
        #pragma unroll
        for (int rt = 0; rt < 2; ++rt) {
            int r = rt * 16 + (l & 15);
            int boff = r * 256 + (((ks * 64) + ((l >> 4) << 4)) ^ ((r & 7) << 4));
            bf16x8 xh = *reinterpret_cast<const bf16x8*>(sXH + boff);
            bf16x8 xl = *reinterpret_cast<const bf16x8*>(sXL + boff);
            #pragma unroll
            for (int ctl = 0; ctl < 2; ++ctl) {
                acc[rt][ctl] = __builtin_amdgcn_mfma_f32_16x16x32_bf16(xh, wh[ctl][ks], acc[rt][ctl], 0, 0, 0);
                acc[rt][ctl] = __builtin_amdgcn_mfma_f32_16x16x32_bf16(xh, wl[ctl][ks], acc[rt][ctl], 0, 0, 0);
                acc[rt][ctl] = __builtin_amdgcn_mfma_f32_16x16x32_bf16(xl, wh[ctl][ks], acc[rt][ctl], 0, 0, 0);
            }
        }
    }

    // epilogue: store h (bf16) + fused alpha. C/D: col=lane&15 (j), row=(lane>>4)*4+reg (n)
    #pragma unroll
    for (int rt = 0; rt < 2; ++rt) {
        #pragma unroll
        for (int reg = 0; reg < 4; ++reg) {
            int n = base + rt * 16 + ((l >> 4) << 2) + reg;
            bool ok = (n < N);
            float v0 = acc[rt][0][reg] + bv[0];
            float v1 = acc[rt][1][reg] + bv[1];
            if (ok) {
                hb[(size_t)n * 128 + jj[0]] = f2bf(v0);
                hb[(size_t)n * 128 + jj[1]] = f2bf(v1);
            }
            float ps = v0 * asw[0] + v1 * asw[1];
            float pd = v0 * adw[0] + v1 * adw[1];
            #pragma unroll
            for (int mask = 1; mask <= 8; mask <<= 1) {
                ps += __shfl_xor(ps, mask);
                pd += __shfl_xor(pd, mask);
            }
            if (ok && (l & 15) == 0) {
                asrc[n * 4 + w] = ps;
                adst[n * 4 + w] = pd;
            }
        }
    }
}

// ------------- CSR build -------------
__global__ __launch_bounds__(256) void k_hist(const int* __restrict__ edges,
                                              int* __restrict__ counts, int E) {
    int e = blockIdx.x * 256 + threadIdx.x;
    if (e < E) atomicAdd(&counts[edges[e * 2]], 1);
}

__global__ __launch_bounds__(256) void k_scan1(const int* __restrict__ counts,
                                               int* __restrict__ partial,
                                               int* __restrict__ bsum, int N) {
    __shared__ int sh[256];
    int i = blockIdx.x * 256 + threadIdx.x;
    sh[threadIdx.x] = (i < N) ? counts[i] : 0;
    __syncthreads();
    for (int off = 1; off < 256; off <<= 1) {
        int v = (threadIdx.x >= off) ? sh[threadIdx.x - off] : 0;
        __syncthreads();
        sh[threadIdx.x] += v;
        __syncthreads();
    }
    if (i < N) partial[i] = sh[threadIdx.x];
    if (threadIdx.x == 255) bsum[blockIdx.x] = sh[255];
}

__global__ __launch_bounds__(256) void k_scan2(int* __restrict__ bsum, int nb) {
    __shared__ int sh[256];
    sh[threadIdx.x] = (threadIdx.x < nb) ? bsum[threadIdx.x] : 0;
    __syncthreads();
    for (int off = 1; off < 256; off <<= 1) {
        int v = (threadIdx.x >= off) ? sh[threadIdx.x - off] : 0;
        __syncthreads();
        sh[threadIdx.x] += v;
        __syncthreads();
    }
    if (threadIdx.x < nb) bsum[threadIdx.x] = sh[threadIdx.x];
}

__global__ __launch_bounds__(256) void k_scan3(const int* __restrict__ partial,
                                               const int* __restrict__ bsum,
                                               const int* __restrict__ counts,
                                               int* __restrict__ row_ptr,
                                               int* __restrict__ cursor, int N) {
    int i = blockIdx.x * 256 + threadIdx.x;
    if (i == 0) row_ptr[0] = 0;
    if (i < N) {
        int incl = partial[i] + (blockIdx.x > 0 ? bsum[blockIdx.x - 1] : 0);
        row_ptr[i + 1] = incl;
        cursor[i] = incl - counts[i];
    }
}

// scatter dst ids into CSR slots (col only; exp is computed in k_node)
__global__ __launch_bounds__(256) void k_scatter(const int* __restrict__ edges,
                                                 int* __restrict__ cursor,
                                                 int* __restrict__ col, int E) {
    int e = blockIdx.x * 256 + threadIdx.x;
    if (e >= E) return;
    int s = edges[e * 2], d = edges[e * 2 + 1];
    int pos = atomicAdd(&cursor[s], 1);
    col[pos] = d;
}

// ------------- per-node: logits+exp on the fly, weighted aggregate of bf16 h -------------
// Softmax is shift-invariant -> no segment max (logits ~N(0,2.8), exp safe in f32).
__global__ __launch_bounds__(256) void k_node(const int* __restrict__ row_ptr,
                                              const int* __restrict__ col,
                                              const float* __restrict__ asrc,
                                              const float* __restrict__ adst,
                                              const unsigned short* __restrict__ hb,
                                              float* __restrict__ out, int N) {
    int n = blockIdx.x * 8 + (threadIdx.x >> 5);
    if (n >= N) return;
    int l = threadIdx.x & 31;      // channels 4l..4l+3
    int hd = l >> 3;
    float asr = asrc[n * 4 + hd];
    int beg = row_ptr[n], end = row_ptr[n + 1];
    float ax = 0.f, ay = 0.f, az = 0.f, aw = 0.f, den = 0.f;
    int k = beg;
    for (; k + 4 <= end; k += 4) {
        int c0 = col[k], c1 = col[k + 1], c2 = col[k + 2], c3 = col[k + 3];
        float g0 = asr + adst[c0 * 4 + hd];
        float g1 = asr + adst[c1 * 4 + hd];
        float g2 = asr + adst[c2 * 4 + hd];
        float g3 = asr + adst[c3 * 4 + hd];
        g0 = (g0 >= 0.f) ? g0 : LRELU_ALPHA * g0;
        g1 = (g1 >= 0.f) ? g1 : LRELU_ALPHA * g1;
        g2 = (g2 >= 0.f) ? g2 : LRELU_ALPHA * g2;
        g3 = (g3 >= 0.f) ? g3 : LRELU_ALPHA * g3;
        float e0 = __expf(g0), e1 = __expf(g1), e2 = __expf(g2), e3 = __expf(g3);
        ushort4 q0 = *reinterpret_cast<const ushort4*>(&hb[(size_t)c0 * 128 + l * 4]);
        ushort4 q1 = *reinterpret_cast<const ushort4*>(&hb[(size_t)c1 * 128 + l * 4]);
        ushort4 q2 = *reinterpret_cast<const ushort4*>(&hb[(size_t)c2 * 128 + l * 4]);
        ushort4 q3 = *reinterpret_cast<const ushort4*>(&hb[(size_t)c3 * 128 + l * 4]);
        ax += e0 * bf2f(q0.x) + e1 * bf2f(q1.x) + e2 * bf2f(q2.x) + e3 * bf2f(q3.x);
        ay += e0 * bf2f(q0.y) + e1 * bf2f(q1.y) + e2 * bf2f(q2.y) + e3 * bf2f(q3.y);
        az += e0 * bf2f(q0.z) + e1 * bf2f(q1.z) + e2 * bf2f(q2.z) + e3 * bf2f(q3.z);
        aw += e0 * bf2f(q0.w) + e1 * bf2f(q1.w) + e2 * bf2f(q2.w) + e3 * bf2f(q3.w);
        den += e0 + e1 + e2 + e3;
    }
    for (; k < end; ++k) {
        int c = col[k];
        float g = asr + adst[c * 4 + hd];
        g = (g >= 0.f) ? g : LRELU_ALPHA * g;
        float e = __expf(g);
        ushort4 q = *reinterpret_cast<const ushort4*>(&hb[(size_t)c * 128 + l * 4]);
        ax += e * bf2f(q.x); ay += e * bf2f(q.y); az += e * bf2f(q.z); aw += e * bf2f(q.w);
        den += e;
    }
    float inv = 1.f / den;
    *reinterpret_cast<float4*>(&out[(size_t)n * 128 + l * 4]) =
        make_float4(ax * inv, ay * inv, az * inv, aw * inv);
}

extern "C" void kernel_launch(void* const* d_in, const int* in_sizes, int n_in,
                              void* d_out, int out_size, void* d_ws, size_t ws_size,
                              hipStream_t stream) {
    const float* x = (const float*)d_in[0];
    const float* W = (const float*)d_in[1];
    const float* b = (const float*)d_in[2];
    const float* a = (const float*)d_in[3];
    const int* edges = (const int*)d_in[4];
    const int N = in_sizes[0] / 128;
    const int E = in_sizes[4] / 2;
    float* out = (float*)d_out;

    char* ws = (char*)d_ws;
    unsigned short* hb = (unsigned short*)ws; ws += (size_t)N * 128 * 2;
    float* asrc = (float*)ws;     ws += (size_t)N * 4 * 4;
    float* adst = (float*)ws;     ws += (size_t)N * 4 * 4;
    int* counts = (int*)ws;       ws += (size_t)N * 4;
    int* partial = (int*)ws;      ws += (size_t)N * 4;
    int* bsum = (int*)ws;         ws += 256 * 4;
    int* row_ptr = (int*)ws;      ws += (size_t)(N + 1) * 4;
    int* cursor = (int*)ws;       ws += (size_t)N * 4;
    int* col = (int*)ws;          ws += (size_t)E * 4;
    bf16x8* wf = (bf16x8*)ws;     ws += (size_t)4096 * 16;   // 64 KB

    const int nb = (N + 255) / 256;
    hipLaunchKernelGGL(k_init, dim3(nb), dim3(256), 0, stream, W, wf, counts, N);
    hipLaunchKernelGGL(k_gemm, dim3((N + 31) / 32), dim3(256), 0, stream,
                       x, wf, b, a, hb, asrc, adst, N);

    const int eb = (E + 255) / 256;
    hipLaunchKernelGGL(k_hist, dim3(eb), dim3(256), 0, stream, edges, counts, E);
    hipLaunchKernelGGL(k_scan1, dim3(nb), dim3(256), 0, stream, counts, partial, bsum, N);
    hipLaunchKernelGGL(k_scan2, dim3(1), dim3(256), 0, stream, bsum, nb);
    hipLaunchKernelGGL(k_scan3, dim3(nb), dim3(256), 0, stream, partial, bsum, counts, row_ptr, cursor, N);
    hipLaunchKernelGGL(k_scatter, dim3(eb), dim3(256), 0, stream, edges, cursor, col, E);

    hipLaunchKernelGGL(k_node, dim3((N + 7) / 8), dim3(256), 0, stream,
                       row_ptr, col, asrc, adst, hb, out, N);
}

// Round 9
// 99.558 us; speedup vs baseline: 1.2784x; 1.0484x over previous
//
#include <hip/hip_runtime.h>
#include <math.h>

#define LRELU_ALPHA 0.2f

typedef __attribute__((ext_vector_type(8))) short bf16x8;
typedef __attribute__((ext_vector_type(4))) float f32x4;

// truncation split: f ~= hi + lo with hi,lo bf16 (RTZ); combined error ~2^-16 rel.
__device__ __forceinline__ void split2(float f0, float f1, unsigned& hi, unsigned& lo) {
    unsigned u0 = __float_as_uint(f0), u1 = __float_as_uint(f1);
    unsigned h0 = u0 & 0xFFFF0000u, h1 = u1 & 0xFFFF0000u;
    float l0f = f0 - __uint_as_float(h0);
    float l1f = f1 - __uint_as_float(h1);
    hi = (h0 >> 16) | h1;
    lo = (__float_as_uint(l0f) >> 16) | (__float_as_uint(l1f) & 0xFFFF0000u);
}
// RNE f32 -> bf16
__device__ __forceinline__ unsigned short f2bf(float f) {
    unsigned u = __float_as_uint(f);
    return (unsigned short)((u + 0x7FFFu + ((u >> 16) & 1u)) >> 16);
}
__device__ __forceinline__ float bf2f(unsigned short s) {
    return __uint_as_float(((unsigned)s) << 16);
}

// ---------------- init: zero counts (all blocks) + W split (blocks 0..7) ----------------
__global__ __launch_bounds__(256) void k_init(const float* __restrict__ W,
                                              bf16x8* __restrict__ wf,
                                              int* __restrict__ counts, int N) {
    int i = blockIdx.x * 256 + threadIdx.x;
    if (i < N) counts[i] = 0;
    if (blockIdx.x < 8) {
        int id = i;   // 0..2047
        int lane = id & 63, ks = (id >> 6) & 3, ct = id >> 8;
        int j = ct * 16 + (lane & 15);
        int k0 = ks * 32 + ((lane >> 4) << 3);
        const float* wp = W + j * 128 + k0;
        float4 f0 = *reinterpret_cast<const float4*>(wp);
        float4 f1 = *reinterpret_cast<const float4*>(wp + 4);
        uint4 hv, lv;
        split2(f0.x, f0.y, hv.x, lv.x);
        split2(f0.z, f0.w, hv.y, lv.y);
        split2(f1.x, f1.y, hv.z, lv.z);
        split2(f1.z, f1.w, hv.w, lv.w);
        *reinterpret_cast<uint4*>(&wf[id]) = hv;
        *reinterpret_cast<uint4*>(&wf[2048 + id]) = lv;
    }
}

// ---------------- MFMA GEMM + fused alpha + fused edge histogram ----------------
// counts[] was zeroed by k_init (previous kernel) -> grid-stride hist here is race-free.
__global__ __launch_bounds__(256) void k_gemm(const float* __restrict__ x,
                                              const bf16x8* __restrict__ wf,
                                              const float* __restrict__ b,
                                              const float* __restrict__ a,
                                              unsigned short* __restrict__ hb,
                                              float* __restrict__ asrc,
                                              float* __restrict__ adst, int N,
                                              const int* __restrict__ edges,
                                              int* __restrict__ counts, int E) {
    __shared__ __align__(16) unsigned char sXH[32 * 256];
    __shared__ __align__(16) unsigned char sXL[32 * 256];
    const int t = threadIdx.x;
    const int w = t >> 6;          // wave 0..3 == head
    const int l = t & 63;
    const int base = blockIdx.x * 32;

    // fused histogram (independent of gemm work; hidden under staging latency)
    for (int e = blockIdx.x * 256 + t; e < E; e += gridDim.x * 256) {
        int2 ed = *reinterpret_cast<const int2*>(&edges[(size_t)e * 2]);
        atomicAdd(&counts[ed.x], 1);
    }

    // W fragments: coalesced 16B loads
    bf16x8 wh[2][4], wl[2][4];
    #pragma unroll
    for (int ctl = 0; ctl < 2; ++ctl)
        #pragma unroll
        for (int ks = 0; ks < 4; ++ks) {
            int fid = (((2 * w + ctl) * 4 + ks) << 6) + l;
            wh[ctl][ks] = wf[fid];
            wl[ctl][ks] = wf[2048 + fid];
        }

    int jj[2];
    float bv[2], asw[2], adw[2];
    #pragma unroll
    for (int ctl = 0; ctl < 2; ++ctl) {
        jj[ctl] = w * 32 + ctl * 16 + (l & 15);
        bv[ctl] = b[jj[ctl]];
        asw[ctl] = a[w * 64 + ctl * 16 + (l & 15)];
        adw[ctl] = a[w * 64 + 32 + ctl * 16 + (l & 15)];
    }

    // stage x tile (32 rows) -> LDS bf16 hi/lo, XOR-swizzled
    #pragma unroll
    for (int i = 0; i < 4; ++i) {
        int f = t + i * 256;            // float4 index in 32x128 tile
        int r = f >> 5, c4 = f & 31;
        int gr = base + r;
        float4 v = (gr < N) ? *reinterpret_cast<const float4*>(x + (size_t)gr * 128 + c4 * 4)
                            : make_float4(0.f, 0.f, 0.f, 0.f);
        unsigned h01, h23, l01, l23;
        split2(v.x, v.y, h01, l01);
        split2(v.z, v.w, h23, l23);
        int boff = r * 256 + ((c4 * 8) ^ ((r & 7) << 4));
        *reinterpret_cast<uint2*>(sXH + boff) = make_uint2(h01, h23);
        *reinterpret_cast<uint2*>(sXL + boff) = make_uint2(l01, l23);
    }
    __syncthreads();

    f32x4 acc[2][2];
    #pragma unroll
    for (int rt = 0; rt < 2; ++rt)
        #pragma unroll
        for (int ctl = 0; ctl < 2; ++ctl)
            acc[rt][ctl] = (f32x4){0.f, 0.f, 0.f, 0.f};

    #pragma unroll
    for (int ks = 0; ks < 4; ++ks) {
        #pragma unroll
        for (int rt = 0; rt < 2; ++rt) {
            int r = rt * 16 + (l & 15);
            int boff = r * 256 + (((ks * 64) + ((l >> 4) << 4)) ^ ((r & 7) << 4));
            bf16x8 xh = *reinterpret_cast<const bf16x8*>(sXH + boff);
            bf16x8 xl = *reinterpret_cast<const bf16x8*>(sXL + boff);
            #pragma unroll
            for (int ctl = 0; ctl < 2; ++ctl) {
                acc[rt][ctl] = __builtin_amdgcn_mfma_f32_16x16x32_bf16(xh, wh[ctl][ks], acc[rt][ctl], 0, 0, 0);
                acc[rt][ctl] = __builtin_amdgcn_mfma_f32_16x16x32_bf16(xh, wl[ctl][ks], acc[rt][ctl], 0, 0, 0);
                acc[rt][ctl] = __builtin_amdgcn_mfma_f32_16x16x32_bf16(xl, wh[ctl][ks], acc[rt][ctl], 0, 0, 0);
            }
        }
    }

    // epilogue: store h (bf16) + fused alpha. C/D: col=lane&15 (j), row=(lane>>4)*4+reg (n)
    #pragma unroll
    for (int rt = 0; rt < 2; ++rt) {
        #pragma unroll
        for (int reg = 0; reg < 4; ++reg) {
            int n = base + rt * 16 + ((l >> 4) << 2) + reg;
            bool ok = (n < N);
            float v0 = acc[rt][0][reg] + bv[0];
            float v1 = acc[rt][1][reg] + bv[1];
            if (ok) {
                hb[(size_t)n * 128 + jj[0]] = f2bf(v0);
                hb[(size_t)n * 128 + jj[1]] = f2bf(v1);
            }
            float ps = v0 * asw[0] + v1 * asw[1];
            float pd = v0 * adw[0] + v1 * adw[1];
            #pragma unroll
            for (int mask = 1; mask <= 8; mask <<= 1) {
                ps += __shfl_xor(ps, mask);
                pd += __shfl_xor(pd, mask);
            }
            if (ok && (l & 15) == 0) {
                asrc[n * 4 + w] = ps;
                adst[n * 4 + w] = pd;
            }
        }
    }
}

// ------------- block-level inclusive scan of counts -------------
__global__ __launch_bounds__(256) void k_scan1(const int* __restrict__ counts,
                                               int* __restrict__ partial,
                                               int* __restrict__ bsum, int N) {
    __shared__ int sh[256];
    int i = blockIdx.x * 256 + threadIdx.x;
    sh[threadIdx.x] = (i < N) ? counts[i] : 0;
    __syncthreads();
    for (int off = 1; off < 256; off <<= 1) {
        int v = (threadIdx.x >= off) ? sh[threadIdx.x - off] : 0;
        __syncthreads();
        sh[threadIdx.x] += v;
        __syncthreads();
    }
    if (i < N) partial[i] = sh[threadIdx.x];
    if (threadIdx.x == 255) bsum[blockIdx.x] = sh[255];
}

// ------------- fused scan2+scan3: each block redundantly scans bsum (nb<=256) in LDS,
// then emits row_ptr + cursor from block-local values only -------------
__global__ __launch_bounds__(256) void k_scan23(const int* __restrict__ partial,
                                                const int* __restrict__ bsum,
                                                const int* __restrict__ counts,
                                                int* __restrict__ row_ptr,
                                                int* __restrict__ cursor, int N, int nb) {
    __shared__ int sh[256];
    int tid = threadIdx.x;
    sh[tid] = (tid < nb) ? bsum[tid] : 0;
    __syncthreads();
    for (int off = 1; off < 256; off <<= 1) {
        int v = (tid >= off) ? sh[tid - off] : 0;
        __syncthreads();
        sh[tid] += v;
        __syncthreads();
    }
    int before = (blockIdx.x > 0) ? sh[blockIdx.x - 1] : 0;
    int i = blockIdx.x * 256 + tid;
    if (i == 0) row_ptr[0] = 0;
    if (i < N) {
        int incl = partial[i] + before;
        row_ptr[i + 1] = incl;
        cursor[i] = incl - counts[i];
    }
}

// scatter dst ids into CSR slots
__global__ __launch_bounds__(256) void k_scatter(const int* __restrict__ edges,
                                                 int* __restrict__ cursor,
                                                 int* __restrict__ col, int E) {
    int e = blockIdx.x * 256 + threadIdx.x;
    if (e >= E) return;
    int2 ed = *reinterpret_cast<const int2*>(&edges[(size_t)e * 2]);
    int pos = atomicAdd(&cursor[ed.x], 1);
    col[pos] = ed.y;
}

// ------------- per-node: logits+exp on the fly, weighted aggregate of bf16 h -------------
// Softmax is shift-invariant -> no segment max (logits ~N(0,2.8), exp safe in f32).
// unroll 8: 8 independent adst + hb gathers in flight per thread (latency-bound loop).
__global__ __launch_bounds__(256) void k_node(const int* __restrict__ row_ptr,
                                              const int* __restrict__ col,
                                              const float* __restrict__ asrc,
                                              const float* __restrict__ adst,
                                              const unsigned short* __restrict__ hb,
                                              float* __restrict__ out, int N) {
    int n = blockIdx.x * 8 + (threadIdx.x >> 5);
    if (n >= N) return;
    int l = threadIdx.x & 31;      // channels 4l..4l+3
    int hd = l >> 3;
    float asr = asrc[n * 4 + hd];
    int beg = row_ptr[n], end = row_ptr[n + 1];
    float ax = 0.f, ay = 0.f, az = 0.f, aw = 0.f, den = 0.f;
    int k = beg;
    for (; k + 8 <= end; k += 8) {
        int c[8];
        #pragma unroll
        for (int u = 0; u < 8; ++u) c[u] = col[k + u];
        float ev[8];
        #pragma unroll
        for (int u = 0; u < 8; ++u) {
            float g = asr + adst[c[u] * 4 + hd];
            g = (g >= 0.f) ? g : LRELU_ALPHA * g;
            ev[u] = __expf(g);
        }
        #pragma unroll
        for (int u = 0; u < 8; ++u) {
            ushort4 q = *reinterpret_cast<const ushort4*>(&hb[(size_t)c[u] * 128 + l * 4]);
            ax += ev[u] * bf2f(q.x); ay += ev[u] * bf2f(q.y);
            az += ev[u] * bf2f(q.z); aw += ev[u] * bf2f(q.w);
            den += ev[u];
        }
    }
    for (; k < end; ++k) {
        int c = col[k];
        float g = asr + adst[c * 4 + hd];
        g = (g >= 0.f) ? g : LRELU_ALPHA * g;
        float e = __expf(g);
        ushort4 q = *reinterpret_cast<const ushort4*>(&hb[(size_t)c * 128 + l * 4]);
        ax += e * bf2f(q.x); ay += e * bf2f(q.y); az += e * bf2f(q.z); aw += e * bf2f(q.w);
        den += e;
    }
    float inv = 1.f / den;
    *reinterpret_cast<float4*>(&out[(size_t)n * 128 + l * 4]) =
        make_float4(ax * inv, ay * inv, az * inv, aw * inv);
}

extern "C" void kernel_launch(void* const* d_in, const int* in_sizes, int n_in,
                              void* d_out, int out_size, void* d_ws, size_t ws_size,
                              hipStream_t stream) {
    const float* x = (const float*)d_in[0];
    const float* W = (const float*)d_in[1];
    const float* b = (const float*)d_in[2];
    const float* a = (const float*)d_in[3];
    const int* edges = (const int*)d_in[4];
    const int N = in_sizes[0] / 128;
    const int E = in_sizes[4] / 2;
    float* out = (float*)d_out;

    char* ws = (char*)d_ws;
    unsigned short* hb = (unsigned short*)ws; ws += (size_t)N * 128 * 2;
    float* asrc = (float*)ws;     ws += (size_t)N * 4 * 4;
    float* adst = (float*)ws;     ws += (size_t)N * 4 * 4;
    int* counts = (int*)ws;       ws += (size_t)N * 4;
    int* partial = (int*)ws;      ws += (size_t)N * 4;
    int* bsum = (int*)ws;         ws += 256 * 4;
    int* row_ptr = (int*)ws;      ws += (size_t)(N + 1) * 4;
    int* cursor = (int*)ws;       ws += (size_t)N * 4;
    int* col = (int*)ws;          ws += (size_t)E * 4;
    bf16x8* wf = (bf16x8*)ws;     ws += (size_t)4096 * 16;   // 64 KB

    const int nb = (N + 255) / 256;
    const int eb = (E + 255) / 256;
    hipLaunchKernelGGL(k_init, dim3(nb), dim3(256), 0, stream, W, wf, counts, N);
    hipLaunchKernelGGL(k_gemm, dim3((N + 31) / 32), dim3(256), 0, stream,
                       x, wf, b, a, hb, asrc, adst, N, edges, counts, E);
    hipLaunchKernelGGL(k_scan1, dim3(nb), dim3(256), 0, stream, counts, partial, bsum, N);
    hipLaunchKernelGGL(k_scan23, dim3(nb), dim3(256), 0, stream,
                       partial, bsum, counts, row_ptr, cursor, N, nb);
    hipLaunchKernelGGL(k_scatter, dim3(eb), dim3(256), 0, stream, edges, cursor, col, E);
    hipLaunchKernelGGL(k_node, dim3((N + 7) / 8), dim3(256), 0, stream,
                       row_ptr, col, asrc, adst, hb, out, N);
}